// Round 11
// baseline (2512.806 us; speedup 1.0000x reference)
//
#include <hip/hip_runtime.h>
#include <hip/hip_cooperative_groups.h>

#define NN 50000
#define EE 600000
#define HH 128
#define EDD 16
#define BB 256
#define LL 5
#define NN16 (NN * 16)
#define NSHADOW 8
#define NTILE 782     // ceil(NN/64)
#define NVAGG 6250    // NN/8
#define NVAGE 3125    // NN/16
#define NSB 196       // ceil(NN/256)

namespace cg = cooperative_groups;

typedef float f32x4 __attribute__((ext_vector_type(4)));
typedef _Float16 f16x4 __attribute__((ext_vector_type(4)));
typedef _Float16 f16x8 __attribute__((ext_vector_type(8)));

struct MegP {
    const float *x, *eattr;
    const float *node_W, *node_b, *edge_W, *edge_b, *mlp1_W, *mlp1_b, *mlp2_W, *mlp2_b;
    const float *vn_w0, *vn_b0, *vn_w1, *vn_b1, *fc_W, *fc_b, *vn_init;
    const int *src, *dst, *batch;
    _Float16 *X0, *X, *Ag, *h16;
    float *aggE, *vn, *pooled8, *outp;
    int *degp, *rowstart, *cursorp;
    int2 *csr_pair;
    int *bsum, *boff, *gstart;
    _Float16 *WtN_h, *WtN_l, *Wt1_h, *Wt1_l, *Wt2_h, *Wt2_l;
};

// ---------------- device helpers (shared by both paths) ----------------
__device__ __forceinline__ void stage_A16(const _Float16* __restrict__ Ag, int brow,
    int tid, _Float16* __restrict__ As)
{
    const int r = tid >> 2, cg_ = tid & 3;
    const int grow = brow + r;
    _Float16* p = As + r * 136 + cg_ * 32;
    if (grow < NN) {
        const f16x8* s = (const f16x8*)(Ag + (size_t)grow * 128 + cg_ * 32);
#pragma unroll
        for (int i = 0; i < 4; ++i) ((f16x8*)p)[i] = s[i];
    } else {
        f16x8 z = (f16x8)(_Float16)0;
#pragma unroll
        for (int i = 0; i < 4; ++i) ((f16x8*)p)[i] = z;
    }
}

__device__ __forceinline__ void mfma_stage16(
    const _Float16* __restrict__ As,
    const _Float16* __restrict__ Wh, const _Float16* __restrict__ Wl,
    int wn, int lm, int quad, int lane, f32x4 acc[4][2])
{
    f16x8 Bh[2][4], Bl[2][4];
#pragma unroll
    for (int nt = 0; nt < 2; ++nt)
#pragma unroll
        for (int ks = 0; ks < 4; ++ks) {
            int fi = ((((wn * 2 + nt) * 4) + ks) * 64 + lane) * 8;
            Bh[nt][ks] = *(const f16x8*)(Wh + fi);
            Bl[nt][ks] = *(const f16x8*)(Wl + fi);
        }
#pragma unroll
    for (int ks = 0; ks < 4; ++ks) {
        f16x8 a[4];
#pragma unroll
        for (int mt = 0; mt < 4; ++mt) {
            int off = (mt * 16 + lm) * 136 + ks * 32 + quad * 8;
            a[mt] = *(const f16x8*)(As + off);
        }
#pragma unroll
        for (int mt = 0; mt < 4; ++mt)
#pragma unroll
            for (int nt = 0; nt < 2; ++nt) {
                acc[mt][nt] = __builtin_amdgcn_mfma_f32_16x16x32_f16(a[mt], Bh[nt][ks], acc[mt][nt], 0, 0, 0);
                acc[mt][nt] = __builtin_amdgcn_mfma_f32_16x16x32_f16(a[mt], Bl[nt][ks], acc[mt][nt], 0, 0, 0);
            }
    }
}

__device__ __forceinline__ void store_f16(const _Float16* __restrict__ Fo,
    _Float16* __restrict__ out, int brow, int tid)
{
    const int r = tid >> 2, cg_ = tid & 3;
    const int grow = brow + r;
    if (grow >= NN) return;
    const f16x8* src = (const f16x8*)(Fo + r * 136 + cg_ * 32);
    f16x8* dst = (f16x8*)(out + (size_t)grow * 128 + cg_ * 32);
#pragma unroll
    for (int i = 0; i < 4; ++i) dst[i] = src[i];
}

__device__ __forceinline__ void wprep_dev(const float* __restrict__ W,
    _Float16* __restrict__ Wh, _Float16* __restrict__ Wl, int total, int gt, int GT)
{
    for (int idx = gt; idx < total; idx += GT) {
        int mat = idx >> 14;
        int r = idx & 16383;
        int j = r & 7, lane = (r >> 3) & 63, ks = (r >> 9) & 3, ntw = (r >> 11) & 7;
        int lm = lane & 15, quad = lane >> 4;
        int n = (ntw >> 1) * 32 + (ntw & 1) * 16 + lm;
        int k = ks * 32 + quad * 8 + j;
        float w = W[(mat << 14) + (k << 7) + n];
        _Float16 h = (_Float16)w;
        Wh[idx] = h;
        Wl[idx] = (_Float16)(w - (float)h);
    }
}

// ================= PATH 1: persistent cooperative mega-kernel =================
__global__ __launch_bounds__(256, 4) void meg_k(MegP P)
{
    cg::grid_group grid = cg::this_grid();
    __shared__ __align__(16) char smraw[64 * 136 * 2];
    _Float16* As = (_Float16*)smraw;
    const int tid = threadIdx.x, bid = blockIdx.x, G = gridDim.x;
    const int gt = bid * 256 + tid, GT = G * 256;

    // ---- phase 0 ----
    for (int i = gt; i < 4 * NN16; i += GT) P.degp[i] = 0;
    for (int i = gt; i < BB * HH; i += GT) P.vn[i] = P.vn_init[i & 127];
    for (int i = gt; i < NSHADOW * BB * HH; i += GT) P.pooled8[i] = 0.f;
    for (int i = gt; i < NN * 32; i += GT) {
        float4 v = ((const float4*)P.x)[i];
        f16x4 o;
        o[0] = (_Float16)v.x; o[1] = (_Float16)v.y; o[2] = (_Float16)v.z; o[3] = (_Float16)v.w;
        ((f16x4*)P.X0)[i] = o;
    }
    wprep_dev(P.node_W, P.WtN_h, P.WtN_l, 5 * 16384, gt, GT);
    wprep_dev(P.mlp1_W, P.Wt1_h, P.Wt1_l, 5 * 16384, gt, GT);
    wprep_dev(P.mlp2_W, P.Wt2_h, P.Wt2_l, 5 * 16384, gt, GT);
    if (bid == 0) {
        int b = tid;
        if (b < BB) {
            int lo = 0, hi = NN;
            while (lo < hi) {
                int mid = (lo + hi) >> 1;
                if (P.batch[mid] < b) lo = mid + 1; else hi = mid;
            }
            P.gstart[b] = lo;
        }
        if (tid == 0) P.gstart[BB] = NN;
    }
    grid.sync();

    // ---- phase 1: degree histogram ----
    for (int e = gt; e < EE; e += GT)
        atomicAdd(&P.degp[(bid & 3) * NN16 + (P.dst[e] << 4)], 1);
    grid.sync();

    // ---- phase 2: per-256-chunk scan ----
    {
        int* s = (int*)smraw;
        for (int vb = bid; vb < NSB; vb += G) {
            int gid = vb * 256 + tid;
            int v = 0;
            if (gid < NN) {
                int o = gid << 4;
                v = P.degp[o] + P.degp[NN16 + o] + P.degp[2 * NN16 + o] + P.degp[3 * NN16 + o];
            }
            s[tid] = v;
            __syncthreads();
            for (int off = 1; off < 256; off <<= 1) {
                int t2 = (tid >= off) ? s[tid - off] : 0;
                __syncthreads();
                s[tid] += t2;
                __syncthreads();
            }
            int incl = s[tid];
            if (gid < NN) P.rowstart[gid] = incl - v;
            if (tid == 255) P.bsum[vb] = incl;
            __syncthreads();
        }
    }
    grid.sync();

    // ---- phase 3: scan block sums ----
    if (bid == 0) {
        int* s = (int*)smraw;
        int v = (tid < NSB) ? P.bsum[tid] : 0;
        s[tid] = v;
        __syncthreads();
        for (int off = 1; off < 256; off <<= 1) {
            int t2 = (tid >= off) ? s[tid - off] : 0;
            __syncthreads();
            s[tid] += t2;
            __syncthreads();
        }
        if (tid < NSB) P.boff[tid] = s[tid] - v;
    }
    grid.sync();

    // ---- phase 4: offsets + cursor ----
    for (int i = gt; i < NN; i += GT) {
        int v = P.rowstart[i] + P.boff[i >> 8];
        P.rowstart[i] = v;
        P.cursorp[i << 4] = v;
    }
    if (gt == 0) P.rowstart[NN] = EE;
    grid.sync();

    // ---- phase 5: fill CSR ----
    for (int e = gt; e < EE; e += GT) {
        int slot = atomicAdd(&P.cursorp[P.dst[e] << 4], 1);
        int2 pr; pr.x = P.src[e]; pr.y = e;
        P.csr_pair[slot] = pr;
    }
    grid.sync();

    // ---- phase 6: aggE ----
    for (int vb = bid; vb < NVAGE; vb += G) {
        const int lane = tid & 15;
        const int node = vb * 16 + (tid >> 4);
        const int s = P.rowstart[node], e = P.rowstart[node + 1];
        float acc = 0.f;
        for (int p = s; p < e; ++p)
            acc += P.eattr[(size_t)P.csr_pair[p].y * 16 + lane];
        P.aggE[(size_t)node * 16 + lane] = acc;
    }
    grid.sync();

    const int lane = tid & 63, wn = tid >> 6, lm = lane & 15, quad = lane >> 4;
    const int colb = wn * 32 + lm;

    for (int l = 0; l < LL; ++l) {
        const _Float16* Wnh = P.WtN_h + l * 16384;
        const _Float16* Wnl = P.WtN_l + l * 16384;
        const _Float16* W1h = P.Wt1_h + l * 16384;
        const _Float16* W1l = P.Wt1_l + l * 16384;
        const _Float16* W2h = P.Wt2_h + l * 16384;
        const _Float16* W2l = P.Wt2_l + l * 16384;
        const float* nb = P.node_b + l * HH;
        const float* b1 = P.mlp1_b + l * HH;
        const float* b2 = P.mlp2_b + l * HH;
        const float* eW = P.edge_W + l * EDD * HH;
        const float* eb = P.edge_b + l * HH;
        const _Float16* xin = (l == 0) ? P.X0 : P.X;

        // ---- A: node encode ----
        for (int t = bid; t < NTILE; t += G) {
            const int brow = t * 64;
            stage_A16(xin, brow, tid, As);
            __syncthreads();
            f32x4 acc[4][2];
#pragma unroll
            for (int mt = 0; mt < 4; ++mt) { acc[mt][0] = (f32x4)(0.f); acc[mt][1] = (f32x4)(0.f); }
            mfma_stage16(As, Wnh, Wnl, wn, lm, quad, lane, acc);
            __syncthreads();
            const float c0 = nb[colb], c1 = nb[colb + 16];
#pragma unroll
            for (int mt = 0; mt < 4; ++mt) {
#pragma unroll
                for (int r = 0; r < 4; ++r) {
                    int trow = mt * 16 + quad * 4 + r;
                    int grow = brow + trow;
                    int bg = P.batch[grow < NN ? grow : NN - 1];
                    const float* vrow = P.vn + (size_t)bg * 128;
                    As[trow * 136 + colb]      = (_Float16)(acc[mt][0][r] + c0 + vrow[colb]);
                    As[trow * 136 + colb + 16] = (_Float16)(acc[mt][1][r] + c1 + vrow[colb + 16]);
                }
            }
            __syncthreads();
            store_f16(As, P.h16, brow, tid);
            __syncthreads();
        }
        grid.sync();

        // ---- B: edge aggregation ----
        {
            float* eWs = (float*)smraw;
            float* ebs = eWs + 16 * 128;
#pragma unroll
            for (int t = 0; t < 2; ++t) {
                int li = (tid + t * 256) * 4;
                *(float4*)(&eWs[li]) = *(const float4*)(eW + li);
            }
            if (tid < 32) *(float4*)(&ebs[tid * 4]) = *(const float4*)(eb + tid * 4);
            __syncthreads();

            const int lane32 = tid & 31, grp = tid >> 5;
            const f16x4* h4 = (const f16x4*)P.h16;
            const float4 b4 = *(const float4*)(&ebs[lane32 * 4]);
            for (int vb = bid; vb < NVAGG; vb += G) {
                const int node = vb * 8 + grp;
                const int s = P.rowstart[node], e = P.rowstart[node + 1];
                float4 acc = make_float4(0.f, 0.f, 0.f, 0.f);
                int p = s;
                for (; p + 4 <= e; p += 4) {
                    int i0 = P.csr_pair[p].x, i1 = P.csr_pair[p + 1].x, i2 = P.csr_pair[p + 2].x, i3 = P.csr_pair[p + 3].x;
                    f16x4 v0 = h4[(size_t)i0 * 32 + lane32];
                    f16x4 v1 = h4[(size_t)i1 * 32 + lane32];
                    f16x4 v2 = h4[(size_t)i2 * 32 + lane32];
                    f16x4 v3 = h4[(size_t)i3 * 32 + lane32];
                    acc.x += (float)v0[0] + (float)v1[0] + (float)v2[0] + (float)v3[0];
                    acc.y += (float)v0[1] + (float)v1[1] + (float)v2[1] + (float)v3[1];
                    acc.z += (float)v0[2] + (float)v1[2] + (float)v2[2] + (float)v3[2];
                    acc.w += (float)v0[3] + (float)v1[3] + (float)v2[3] + (float)v3[3];
                }
                for (; p < e; ++p) {
                    f16x4 v = h4[(size_t)P.csr_pair[p].x * 32 + lane32];
                    acc.x += (float)v[0]; acc.y += (float)v[1]; acc.z += (float)v[2]; acc.w += (float)v[3];
                }
                const float degf = (float)(e - s);
                const float* ae = P.aggE + (size_t)node * 16;
                float4 et = make_float4(degf * b4.x, degf * b4.y, degf * b4.z, degf * b4.w);
#pragma unroll
                for (int k = 0; k < 16; ++k) {
                    float a = ae[k];
                    float4 w = *(const float4*)(&eWs[k * 128 + lane32 * 4]);
                    et.x = fmaf(a, w.x, et.x);
                    et.y = fmaf(a, w.y, et.y);
                    et.z = fmaf(a, w.z, et.z);
                    et.w = fmaf(a, w.w, et.w);
                }
                acc.x += et.x; acc.y += et.y; acc.z += et.z; acc.w += et.w;
                f16x4 o;
                o[0] = (_Float16)acc.x; o[1] = (_Float16)acc.y; o[2] = (_Float16)acc.z; o[3] = (_Float16)acc.w;
                ((f16x4*)P.Ag)[(size_t)node * 32 + lane32] = o;
            }
        }
        grid.sync();

        // ---- C: fused MLP + pooled partials ----
        for (int t = bid; t < NTILE; t += G) {
            const int brow = t * 64;
            stage_A16(P.Ag, brow, tid, As);
            __syncthreads();
            f32x4 acc[4][2];
#pragma unroll
            for (int mt = 0; mt < 4; ++mt) { acc[mt][0] = (f32x4)(0.f); acc[mt][1] = (f32x4)(0.f); }
            mfma_stage16(As, W1h, W1l, wn, lm, quad, lane, acc);
            __syncthreads();
            {
                const float c0 = b1[colb], c1 = b1[colb + 16];
#pragma unroll
                for (int mt = 0; mt < 4; ++mt) {
#pragma unroll
                    for (int r = 0; r < 4; ++r) {
                        int trow = mt * 16 + quad * 4 + r;
                        As[trow * 136 + colb]      = (_Float16)fmaxf(acc[mt][0][r] + c0, 0.f);
                        As[trow * 136 + colb + 16] = (_Float16)fmaxf(acc[mt][1][r] + c1, 0.f);
                    }
                }
            }
            __syncthreads();
#pragma unroll
            for (int mt = 0; mt < 4; ++mt) { acc[mt][0] = (f32x4)(0.f); acc[mt][1] = (f32x4)(0.f); }
            mfma_stage16(As, W2h, W2l, wn, lm, quad, lane, acc);
            __syncthreads();
            {
                const float d0 = b2[colb], d1 = b2[colb + 16];
#pragma unroll
                for (int mt = 0; mt < 4; ++mt) {
#pragma unroll
                    for (int r = 0; r < 4; ++r) {
                        int trow = mt * 16 + quad * 4 + r;
                        As[trow * 136 + colb]      = (_Float16)fmaxf(acc[mt][0][r] + d0, 0.f);
                        As[trow * 136 + colb + 16] = (_Float16)fmaxf(acc[mt][1][r] + d1, 0.f);
                    }
                }
            }
            __syncthreads();
            store_f16(As, P.X, brow, tid);
            {
                float* pooled = P.pooled8 + (size_t)(t & (NSHADOW - 1)) * (BB * HH);
                const int c = tid & 127, half = tid >> 7;
                const int row0 = half * 32;
                float sum = 0.f;
                int curg = -1;
                for (int r2 = 0; r2 < 32; ++r2) {
                    int grow = brow + row0 + r2;
                    if (grow >= NN) break;
                    int g = P.batch[grow];
                    if (g != curg) {
                        if (curg >= 0) atomicAdd(&pooled[curg * 128 + c], sum);
                        curg = g; sum = 0.f;
                    }
                    sum += (float)As[(row0 + r2) * 136 + c];
                }
                if (curg >= 0) atomicAdd(&pooled[curg * 128 + c], sum);
            }
            __syncthreads();
        }
        grid.sync();

        // ---- D: VN update ----
        if (l < LL - 1) {
            if (bid < BB) {
                float* p = (float*)smraw;
                float* q = p + 128;
                const int g = bid;
                if (tid < 128) {
                    float cnt = (float)(P.gstart[g + 1] - P.gstart[g]);
                    if (cnt < 1.f) cnt = 1.f;
                    float sum = 0.f;
#pragma unroll
                    for (int s = 0; s < NSHADOW; ++s) {
                        float* slot = P.pooled8 + (size_t)s * (BB * HH) + g * 128 + tid;
                        sum += *slot;
                        *slot = 0.f;
                    }
                    p[tid] = sum / cnt;
                }
                __syncthreads();
                if (tid < 128) {
                    float a0 = P.vn_b0[tid];
                    for (int k = 0; k < 128; ++k) a0 = fmaf(p[k], P.vn_w0[k * 128 + tid], a0);
                    q[tid] = fmaxf(a0, 0.f);
                }
                __syncthreads();
                if (tid < 128) {
                    float a1 = P.vn_b1[tid];
                    for (int k = 0; k < 128; ++k) a1 = fmaf(q[k], P.vn_w1[k * 128 + tid], a1);
                    P.vn[g * 128 + tid] += fmaxf(a1, 0.f);
                }
            }
            grid.sync();
        }
    }

    grid.sync();
    if (bid < BB) {
        float* p = (float*)smraw;
        const int g = bid;
        if (tid < 128) {
            float cnt = (float)(P.gstart[g + 1] - P.gstart[g]);
            if (cnt < 1.f) cnt = 1.f;
            float sum = 0.f;
#pragma unroll
            for (int s = 0; s < NSHADOW; ++s)
                sum += P.pooled8[(size_t)s * (BB * HH) + g * 128 + tid];
            p[tid] = sum / cnt;
        }
        __syncthreads();
        if (tid < 128) {
            float acc = P.fc_b[tid];
            for (int k = 0; k < 128; ++k) acc = fmaf(p[k], P.fc_W[k * 128 + tid], acc);
            P.outp[g * 128 + tid] = acc;
        }
    }
}

// ================= PATH 2: fallback multi-kernel (R9, proven 595 µs) =================
__global__ __launch_bounds__(256) void wprep_k(const float* __restrict__ W,
    _Float16* __restrict__ Wh, _Float16* __restrict__ Wl, int total)
{
    int idx = blockIdx.x * 256 + threadIdx.x;
    if (idx >= total) return;
    wprep_dev(W, Wh, Wl, total, idx, 1 << 30);
}

__global__ __launch_bounds__(256) void xprep_k(const float* __restrict__ x, _Float16* __restrict__ X)
{
    int i = blockIdx.x * 256 + threadIdx.x;
    if (i >= NN * 32) return;
    float4 v = ((const float4*)x)[i];
    f16x4 o;
    o[0] = (_Float16)v.x; o[1] = (_Float16)v.y; o[2] = (_Float16)v.z; o[3] = (_Float16)v.w;
    ((f16x4*)X)[i] = o;
}

__global__ __launch_bounds__(256) void gemm_node_k(
    const _Float16* __restrict__ Ag,
    const _Float16* __restrict__ Wh, const _Float16* __restrict__ Wl,
    const float* __restrict__ bias, _Float16* __restrict__ out,
    const float* __restrict__ vn, const int* __restrict__ batch)
{
    __shared__ __align__(16) _Float16 smem[64 * 136];
    const int tid = threadIdx.x, brow = blockIdx.x * 64;
    stage_A16(Ag, brow, tid, smem);
    __syncthreads();
    const int lane = tid & 63, wn = tid >> 6, lm = lane & 15, quad = lane >> 4;
    f32x4 acc[4][2];
#pragma unroll
    for (int mt = 0; mt < 4; ++mt) { acc[mt][0] = (f32x4)(0.f); acc[mt][1] = (f32x4)(0.f); }
    mfma_stage16(smem, Wh, Wl, wn, lm, quad, lane, acc);
    __syncthreads();
    const int colb = wn * 32 + lm;
    const float b0 = bias[colb], b1 = bias[colb + 16];
#pragma unroll
    for (int mt = 0; mt < 4; ++mt) {
#pragma unroll
        for (int r = 0; r < 4; ++r) {
            int trow = mt * 16 + quad * 4 + r;
            int grow = brow + trow;
            int bg = batch[grow < NN ? grow : NN - 1];
            const float* vrow = vn + (size_t)bg * 128;
            smem[trow * 136 + colb]      = (_Float16)(acc[mt][0][r] + b0 + vrow[colb]);
            smem[trow * 136 + colb + 16] = (_Float16)(acc[mt][1][r] + b1 + vrow[colb + 16]);
        }
    }
    __syncthreads();
    store_f16(smem, out, brow, tid);
}

__global__ __launch_bounds__(256) void gemm_mlp_k(
    const _Float16* __restrict__ Ag,
    const _Float16* __restrict__ W1h, const _Float16* __restrict__ W1l, const float* __restrict__ b1,
    const _Float16* __restrict__ W2h, const _Float16* __restrict__ W2l, const float* __restrict__ b2,
    _Float16* __restrict__ X, float* __restrict__ pooled8, const int* __restrict__ batch)
{
    __shared__ __align__(16) _Float16 smem[64 * 136];
    const int tid = threadIdx.x, brow = blockIdx.x * 64;
    stage_A16(Ag, brow, tid, smem);
    __syncthreads();
    const int lane = tid & 63, wn = tid >> 6, lm = lane & 15, quad = lane >> 4;
    const int colb = wn * 32 + lm;
    f32x4 acc[4][2];
#pragma unroll
    for (int mt = 0; mt < 4; ++mt) { acc[mt][0] = (f32x4)(0.f); acc[mt][1] = (f32x4)(0.f); }
    mfma_stage16(smem, W1h, W1l, wn, lm, quad, lane, acc);
    __syncthreads();
    {
        const float c0 = b1[colb], c1 = b1[colb + 16];
#pragma unroll
        for (int mt = 0; mt < 4; ++mt) {
#pragma unroll
            for (int r = 0; r < 4; ++r) {
                int trow = mt * 16 + quad * 4 + r;
                smem[trow * 136 + colb]      = (_Float16)fmaxf(acc[mt][0][r] + c0, 0.f);
                smem[trow * 136 + colb + 16] = (_Float16)fmaxf(acc[mt][1][r] + c1, 0.f);
            }
        }
    }
    __syncthreads();
#pragma unroll
    for (int mt = 0; mt < 4; ++mt) { acc[mt][0] = (f32x4)(0.f); acc[mt][1] = (f32x4)(0.f); }
    mfma_stage16(smem, W2h, W2l, wn, lm, quad, lane, acc);
    __syncthreads();
    {
        const float d0 = b2[colb], d1 = b2[colb + 16];
#pragma unroll
        for (int mt = 0; mt < 4; ++mt) {
#pragma unroll
            for (int r = 0; r < 4; ++r) {
                int trow = mt * 16 + quad * 4 + r;
                smem[trow * 136 + colb]      = (_Float16)fmaxf(acc[mt][0][r] + d0, 0.f);
                smem[trow * 136 + colb + 16] = (_Float16)fmaxf(acc[mt][1][r] + d1, 0.f);
            }
        }
    }
    __syncthreads();
    store_f16(smem, X, brow, tid);
    {
        float* pooled = pooled8 + (size_t)(blockIdx.x & (NSHADOW - 1)) * (BB * HH);
        const int c = tid & 127, half = tid >> 7;
        const int row0 = half * 32;
        float sum = 0.f;
        int curg = -1;
        for (int r2 = 0; r2 < 32; ++r2) {
            int grow = brow + row0 + r2;
            if (grow >= NN) break;
            int g = batch[grow];
            if (g != curg) {
                if (curg >= 0) atomicAdd(&pooled[curg * 128 + c], sum);
                curg = g; sum = 0.f;
            }
            sum += (float)smem[(row0 + r2) * 136 + c];
        }
        if (curg >= 0) atomicAdd(&pooled[curg * 128 + c], sum);
    }
}

__global__ __launch_bounds__(256) void aggregate_k(
    const _Float16* __restrict__ h, const float* __restrict__ aggE,
    const float* __restrict__ eW, const float* __restrict__ eb,
    const int* __restrict__ rowstart, const int2* __restrict__ csr_pair,
    _Float16* __restrict__ Ag)
{
    __shared__ float eWs[16 * 128];
    __shared__ float ebs[128];
    const int tid = threadIdx.x;
#pragma unroll
    for (int t = 0; t < 2; ++t) {
        int li = (tid + t * 256) * 4;
        *(float4*)(&eWs[li]) = *(const float4*)(eW + li);
    }
    if (tid < 32) *(float4*)(&ebs[tid * 4]) = *(const float4*)(eb + tid * 4);
    __syncthreads();
    const int lane = tid & 31;
    const int node = blockIdx.x * 8 + (tid >> 5);
    if (node >= NN) return;
    const int s = rowstart[node], e = rowstart[node + 1];
    const f16x4* h4 = (const f16x4*)h;
    float4 acc = make_float4(0.f, 0.f, 0.f, 0.f);
    int p = s;
    for (; p + 4 <= e; p += 4) {
        int s0 = csr_pair[p].x, s1 = csr_pair[p + 1].x, s2 = csr_pair[p + 2].x, s3 = csr_pair[p + 3].x;
        f16x4 v0 = h4[(size_t)s0 * 32 + lane];
        f16x4 v1 = h4[(size_t)s1 * 32 + lane];
        f16x4 v2 = h4[(size_t)s2 * 32 + lane];
        f16x4 v3 = h4[(size_t)s3 * 32 + lane];
        acc.x += (float)v0[0] + (float)v1[0] + (float)v2[0] + (float)v3[0];
        acc.y += (float)v0[1] + (float)v1[1] + (float)v2[1] + (float)v3[1];
        acc.z += (float)v0[2] + (float)v1[2] + (float)v2[2] + (float)v3[2];
        acc.w += (float)v0[3] + (float)v1[3] + (float)v2[3] + (float)v3[3];
    }
    for (; p < e; ++p) {
        f16x4 v = h4[(size_t)csr_pair[p].x * 32 + lane];
        acc.x += (float)v[0]; acc.y += (float)v[1]; acc.z += (float)v[2]; acc.w += (float)v[3];
    }
    const float degf = (float)(e - s);
    const float* ae = aggE + (size_t)node * 16;
    const float4 b4 = *(const float4*)(&ebs[lane * 4]);
    float4 et = make_float4(degf * b4.x, degf * b4.y, degf * b4.z, degf * b4.w);
#pragma unroll
    for (int k = 0; k < 16; ++k) {
        float a = ae[k];
        float4 w = *(const float4*)(&eWs[k * 128 + lane * 4]);
        et.x = fmaf(a, w.x, et.x);
        et.y = fmaf(a, w.y, et.y);
        et.z = fmaf(a, w.z, et.z);
        et.w = fmaf(a, w.w, et.w);
    }
    acc.x += et.x; acc.y += et.y; acc.z += et.z; acc.w += et.w;
    f16x4 o;
    o[0] = (_Float16)acc.x; o[1] = (_Float16)acc.y; o[2] = (_Float16)acc.z; o[3] = (_Float16)acc.w;
    ((f16x4*)Ag)[(size_t)node * 32 + lane] = o;
}

__global__ __launch_bounds__(256) void aggE_k(
    const float* __restrict__ eattr, const int* __restrict__ rowstart,
    const int2* __restrict__ csr_pair, float* __restrict__ aggE)
{
    const int lane = threadIdx.x & 15;
    const int node = blockIdx.x * 16 + (threadIdx.x >> 4);
    if (node >= NN) return;
    const int s = rowstart[node], e = rowstart[node + 1];
    float acc = 0.f;
    for (int p = s; p < e; ++p)
        acc += eattr[(size_t)csr_pair[p].y * 16 + lane];
    aggE[(size_t)node * 16 + lane] = acc;
}

__global__ __launch_bounds__(128) void vn_update_k(
    float* __restrict__ pooled8, const int* __restrict__ gstart,
    const float* __restrict__ W0, const float* __restrict__ b0,
    const float* __restrict__ W1, const float* __restrict__ b1,
    float* __restrict__ vn)
{
    __shared__ float p[128], q[128];
    const int g = blockIdx.x, t = threadIdx.x;
    float cnt = (float)(gstart[g + 1] - gstart[g]);
    if (cnt < 1.f) cnt = 1.f;
    float sum = 0.f;
#pragma unroll
    for (int s = 0; s < NSHADOW; ++s) {
        float* slot = pooled8 + (size_t)s * (BB * HH) + g * 128 + t;
        sum += *slot;
        *slot = 0.f;
    }
    p[t] = sum / cnt;
    __syncthreads();
    float a0 = b0[t];
    for (int k = 0; k < 128; ++k) a0 = fmaf(p[k], W0[k * 128 + t], a0);
    q[t] = fmaxf(a0, 0.f);
    __syncthreads();
    float a1 = b1[t];
    for (int k = 0; k < 128; ++k) a1 = fmaf(q[k], W1[k * 128 + t], a1);
    vn[g * 128 + t] += fmaxf(a1, 0.f);
}

__global__ __launch_bounds__(128) void fc_k(
    const float* __restrict__ pooled8, const int* __restrict__ gstart,
    const float* __restrict__ W, const float* __restrict__ b, float* __restrict__ out)
{
    __shared__ float p[128];
    const int g = blockIdx.x, t = threadIdx.x;
    float cnt = (float)(gstart[g + 1] - gstart[g]);
    if (cnt < 1.f) cnt = 1.f;
    float sum = 0.f;
#pragma unroll
    for (int s = 0; s < NSHADOW; ++s)
        sum += pooled8[(size_t)s * (BB * HH) + g * 128 + t];
    p[t] = sum / cnt;
    __syncthreads();
    float acc = b[t];
    for (int k = 0; k < 128; ++k) acc = fmaf(p[k], W[k * 128 + t], acc);
    out[g * 128 + t] = acc;
}

__global__ void histp_k(const int* __restrict__ idx, int n, int* __restrict__ cntp)
{
    int i = blockIdx.x * 256 + threadIdx.x;
    if (i < n) atomicAdd(&cntp[(blockIdx.x & 3) * NN16 + (idx[i] << 4)], 1);
}

__global__ void scan_deg_k(const int* __restrict__ degp, int n, int* __restrict__ out, int* __restrict__ bsum)
{
    __shared__ int s[256];
    int gid = blockIdx.x * 256 + threadIdx.x;
    int v = 0;
    if (gid < n) {
        int o = gid << 4;
        v = degp[o] + degp[NN16 + o] + degp[2 * NN16 + o] + degp[3 * NN16 + o];
    }
    s[threadIdx.x] = v;
    __syncthreads();
    for (int off = 1; off < 256; off <<= 1) {
        int t = (threadIdx.x >= off) ? s[threadIdx.x - off] : 0;
        __syncthreads();
        s[threadIdx.x] += t;
        __syncthreads();
    }
    int incl = s[threadIdx.x];
    if (gid < n) out[gid] = incl - v;
    if (bsum != nullptr && threadIdx.x == 255) bsum[blockIdx.x] = incl;
}

__global__ void scan_k(const int* __restrict__ in, int n, int* __restrict__ out, int* __restrict__ bsum)
{
    __shared__ int s[256];
    int gid = blockIdx.x * 256 + threadIdx.x;
    int v = (gid < n) ? in[gid] : 0;
    s[threadIdx.x] = v;
    __syncthreads();
    for (int off = 1; off < 256; off <<= 1) {
        int t = (threadIdx.x >= off) ? s[threadIdx.x - off] : 0;
        __syncthreads();
        s[threadIdx.x] += t;
        __syncthreads();
    }
    int incl = s[threadIdx.x];
    if (gid < n) out[gid] = incl - v;
    if (bsum != nullptr && threadIdx.x == 255) bsum[blockIdx.x] = incl;
}

__global__ void addoff_k(int* __restrict__ data, const int* __restrict__ boff, int n, int total)
{
    int i = blockIdx.x * 256 + threadIdx.x;
    if (i < n) data[i] += boff[blockIdx.x];
    if (i == 0) data[n] = total;
}

__global__ void curinit_k(const int* __restrict__ rowstart, int* __restrict__ cursorp)
{
    int i = blockIdx.x * 256 + threadIdx.x;
    if (i < NN) cursorp[i << 4] = rowstart[i];
}

__global__ void fill_k(const int* __restrict__ dst, const int* __restrict__ src, int n,
                       int* __restrict__ cursorp, int2* __restrict__ csr_pair)
{
    int e = blockIdx.x * 256 + threadIdx.x;
    if (e < n) {
        int slot = atomicAdd(&cursorp[dst[e] << 4], 1);
        int2 pr; pr.x = src[e]; pr.y = e;
        csr_pair[slot] = pr;
    }
}

__global__ void gstart_k(const int* __restrict__ batch, int* __restrict__ gstart)
{
    int b = blockIdx.x * 64 + threadIdx.x;
    if (b > BB) return;
    if (b == BB) { gstart[BB] = NN; return; }
    int lo = 0, hi = NN;
    while (lo < hi) {
        int mid = (lo + hi) >> 1;
        if (batch[mid] < b) lo = mid + 1; else hi = mid;
    }
    gstart[b] = lo;
}

__global__ void vninit_k(const float* __restrict__ vninit, float* __restrict__ vn, float* __restrict__ pooled8)
{
    int i = blockIdx.x * 256 + threadIdx.x;
    if (i < BB * HH) vn[i] = vninit[i & 127];
    if (i < NSHADOW * BB * HH) pooled8[i] = 0.f;
}

// ---------------- Launch ----------------
extern "C" void kernel_launch(void* const* d_in, const int* in_sizes, int n_in,
                              void* d_out, int out_size, void* d_ws, size_t ws_size,
                              hipStream_t stream)
{
    (void)in_sizes; (void)n_in; (void)out_size; (void)ws_size;
    MegP P;
    P.x       = (const float*)d_in[0];
    P.eattr   = (const float*)d_in[1];
    P.node_W  = (const float*)d_in[2];
    P.node_b  = (const float*)d_in[3];
    P.edge_W  = (const float*)d_in[4];
    P.edge_b  = (const float*)d_in[5];
    P.mlp1_W  = (const float*)d_in[6];
    P.mlp1_b  = (const float*)d_in[7];
    P.mlp2_W  = (const float*)d_in[8];
    P.mlp2_b  = (const float*)d_in[9];
    P.vn_w0   = (const float*)d_in[10];
    P.vn_b0   = (const float*)d_in[11];
    P.vn_w1   = (const float*)d_in[12];
    P.vn_b1   = (const float*)d_in[13];
    P.fc_W    = (const float*)d_in[14];
    P.fc_b    = (const float*)d_in[15];
    P.vn_init = (const float*)d_in[16];
    const int* eidx = (const int*)d_in[17];
    P.src   = eidx;
    P.dst   = eidx + EE;
    P.batch = (const int*)d_in[18];
    P.outp  = (float*)d_out;

    char* wp = (char*)d_ws;
    auto alloc = [&](size_t bytes) -> void* {
        void* p = (void*)wp;
        wp += (bytes + 255) & ~(size_t)255;
        return p;
    };
    P.X0      = (_Float16*)alloc((size_t)NN * HH * 2);
    P.X       = (_Float16*)alloc((size_t)NN * HH * 2);
    P.Ag      = (_Float16*)alloc((size_t)NN * HH * 2);
    P.h16     = (_Float16*)alloc((size_t)NN * HH * 2);
    P.aggE    = (float*)alloc((size_t)NN * EDD * 4);
    P.vn      = (float*)alloc((size_t)BB * HH * 4);
    P.pooled8 = (float*)alloc((size_t)NSHADOW * BB * HH * 4);
    P.degp    = (int*)alloc((size_t)4 * NN16 * 4);
    P.rowstart= (int*)alloc((size_t)(NN + 1) * 4);
    P.cursorp = (int*)alloc((size_t)NN16 * 4);
    P.csr_pair= (int2*)alloc((size_t)EE * 8);
    P.bsum    = (int*)alloc(256 * 4);
    P.boff    = (int*)alloc(256 * 4);
    P.gstart  = (int*)alloc((size_t)(BB + 1) * 4);
    P.WtN_h   = (_Float16*)alloc((size_t)5 * 16384 * 2);
    P.WtN_l   = (_Float16*)alloc((size_t)5 * 16384 * 2);
    P.Wt1_h   = (_Float16*)alloc((size_t)5 * 16384 * 2);
    P.Wt1_l   = (_Float16*)alloc((size_t)5 * 16384 * 2);
    P.Wt2_h   = (_Float16*)alloc((size_t)5 * 16384 * 2);
    P.Wt2_l   = (_Float16*)alloc((size_t)5 * 16384 * 2);

    // ---- try cooperative path with occupancy-derived grid ----
    int numBlocksPerCU = 0;
    hipError_t qerr = hipOccupancyMaxActiveBlocksPerMultiprocessor(&numBlocksPerCU, meg_k, 256, 0);
    int numCU = 0;
    hipError_t derr = hipDeviceGetAttribute(&numCU, hipDeviceAttributeMultiprocessorCount, 0);
    hipError_t lerr = hipErrorUnknown;
    if (qerr == hipSuccess && derr == hipSuccess && numBlocksPerCU >= 1 && numCU >= 1) {
        int grid = numBlocksPerCU * numCU;
        if (grid > 2048) grid = 2048;
        if (grid >= 256) {
            void* kargs[] = { &P };
            lerr = hipLaunchCooperativeKernel(meg_k, dim3(grid), dim3(256), kargs, 0, stream);
        }
    }
    if (lerr == hipSuccess) return;

    // ---- fallback: proven multi-kernel path ----
    hipMemsetAsync(P.degp, 0, (size_t)4 * NN16 * 4, stream);
    histp_k<<<(EE + 255) / 256, 256, 0, stream>>>(P.dst, EE, P.degp);
    const int NB1 = (NN + 255) / 256;
    scan_deg_k<<<NB1, 256, 0, stream>>>(P.degp, NN, P.rowstart, P.bsum);
    scan_k<<<1, 256, 0, stream>>>(P.bsum, NB1, P.boff, nullptr);
    addoff_k<<<NB1, 256, 0, stream>>>(P.rowstart, P.boff, NN, EE);
    curinit_k<<<NB1, 256, 0, stream>>>(P.rowstart, P.cursorp);
    fill_k<<<(EE + 255) / 256, 256, 0, stream>>>(P.dst, P.src, EE, P.cursorp, P.csr_pair);
    gstart_k<<<5, 64, 0, stream>>>(P.batch, P.gstart);
    aggE_k<<<(NN + 15) / 16, 256, 0, stream>>>(P.eattr, P.rowstart, P.csr_pair, P.aggE);
    vninit_k<<<(NSHADOW * BB * HH) / 256, 256, 0, stream>>>(P.vn_init, P.vn, P.pooled8);
    xprep_k<<<(NN * 32 + 255) / 256, 256, 0, stream>>>(P.x, P.X0);
    wprep_k<<<(5 * 16384 + 255) / 256, 256, 0, stream>>>(P.node_W, P.WtN_h, P.WtN_l, 5 * 16384);
    wprep_k<<<(5 * 16384 + 255) / 256, 256, 0, stream>>>(P.mlp1_W, P.Wt1_h, P.Wt1_l, 5 * 16384);
    wprep_k<<<(5 * 16384 + 255) / 256, 256, 0, stream>>>(P.mlp2_W, P.Wt2_h, P.Wt2_l, 5 * 16384);

    const int GN = (NN + 63) / 64;
    const _Float16* xin = P.X0;
    for (int l = 0; l < LL; ++l) {
        gemm_node_k<<<GN, 256, 0, stream>>>(xin,
            P.WtN_h + (size_t)l * 16384, P.WtN_l + (size_t)l * 16384,
            P.node_b + (size_t)l * HH, P.h16, P.vn, P.batch);
        aggregate_k<<<(NN + 7) / 8, 256, 0, stream>>>(P.h16, P.aggE,
            P.edge_W + (size_t)l * EDD * HH, P.edge_b + (size_t)l * HH,
            P.rowstart, P.csr_pair, P.Ag);
        gemm_mlp_k<<<GN, 256, 0, stream>>>(P.Ag,
            P.Wt1_h + (size_t)l * 16384, P.Wt1_l + (size_t)l * 16384, P.mlp1_b + (size_t)l * HH,
            P.Wt2_h + (size_t)l * 16384, P.Wt2_l + (size_t)l * 16384, P.mlp2_b + (size_t)l * HH,
            P.X, P.pooled8, P.batch);
        if (l < LL - 1)
            vn_update_k<<<BB, 128, 0, stream>>>(P.pooled8, P.gstart, P.vn_w0, P.vn_b0, P.vn_w1, P.vn_b1, P.vn);
        xin = P.X;
    }
    fc_k<<<BB, 128, 0, stream>>>(P.pooled8, P.gstart, P.fc_W, P.fc_b, P.outp);
}

// Round 12
// 630.343 us; speedup vs baseline: 3.9864x; 3.9864x over previous
//
#include <hip/hip_runtime.h>

#define NN 50000
#define EE 600000
#define HH 128
#define EDD 16
#define BB 256
#define LL 5
#define NN16 (NN * 16)
#define NSHADOW 8

typedef float f32x4 __attribute__((ext_vector_type(4)));
typedef _Float16 f16x4 __attribute__((ext_vector_type(4)));
typedef _Float16 f16x8 __attribute__((ext_vector_type(8)));
typedef unsigned long long u64;

// ---------------- shared device helpers ----------------
__device__ __forceinline__ void stage_A16(const _Float16* __restrict__ Ag, int brow,
    int tid, _Float16* __restrict__ As)
{
    const int r = tid >> 2, cg_ = tid & 3;
    const int grow = brow + r;
    _Float16* p = As + r * 136 + cg_ * 32;
    if (grow < NN) {
        const f16x8* s = (const f16x8*)(Ag + (size_t)grow * 128 + cg_ * 32);
#pragma unroll
        for (int i = 0; i < 4; ++i) ((f16x8*)p)[i] = s[i];
    } else {
        f16x8 z = (f16x8)(_Float16)0;
#pragma unroll
        for (int i = 0; i < 4; ++i) ((f16x8*)p)[i] = z;
    }
}

__device__ __forceinline__ void mfma_stage16(
    const _Float16* __restrict__ As,
    const _Float16* __restrict__ Wh, const _Float16* __restrict__ Wl,
    int wn, int lm, int quad, int lane, f32x4 acc[4][2])
{
    f16x8 Bh[2][4], Bl[2][4];
#pragma unroll
    for (int nt = 0; nt < 2; ++nt)
#pragma unroll
        for (int ks = 0; ks < 4; ++ks) {
            int fi = ((((wn * 2 + nt) * 4) + ks) * 64 + lane) * 8;
            Bh[nt][ks] = *(const f16x8*)(Wh + fi);
            Bl[nt][ks] = *(const f16x8*)(Wl + fi);
        }
#pragma unroll
    for (int ks = 0; ks < 4; ++ks) {
        f16x8 a[4];
#pragma unroll
        for (int mt = 0; mt < 4; ++mt) {
            int off = (mt * 16 + lm) * 136 + ks * 32 + quad * 8;
            a[mt] = *(const f16x8*)(As + off);
        }
#pragma unroll
        for (int mt = 0; mt < 4; ++mt)
#pragma unroll
            for (int nt = 0; nt < 2; ++nt) {
                acc[mt][nt] = __builtin_amdgcn_mfma_f32_16x16x32_f16(a[mt], Bh[nt][ks], acc[mt][nt], 0, 0, 0);
                acc[mt][nt] = __builtin_amdgcn_mfma_f32_16x16x32_f16(a[mt], Bl[nt][ks], acc[mt][nt], 0, 0, 0);
            }
    }
}

__device__ __forceinline__ void store_f16(const _Float16* __restrict__ Fo,
    _Float16* __restrict__ out, int brow, int tid)
{
    const int r = tid >> 2, cg_ = tid & 3;
    const int grow = brow + r;
    if (grow >= NN) return;
    const f16x8* src = (const f16x8*)(Fo + r * 136 + cg_ * 32);
    f16x8* dst = (f16x8*)(out + (size_t)grow * 128 + cg_ * 32);
#pragma unroll
    for (int i = 0; i < 4; ++i) dst[i] = src[i];
}

__device__ __forceinline__ void wprep_dev(const float* __restrict__ W,
    _Float16* __restrict__ Wh, _Float16* __restrict__ Wl, int total, int gt, int GT)
{
    for (int idx = gt; idx < total; idx += GT) {
        int mat = idx >> 14;
        int r = idx & 16383;
        int j = r & 7, lane = (r >> 3) & 63, ks = (r >> 9) & 3, ntw = (r >> 11) & 7;
        int lm = lane & 15, quad = lane >> 4;
        int n = (ntw >> 1) * 32 + (ntw & 1) * 16 + lm;
        int k = ks * 32 + quad * 8 + j;
        float w = W[(mat << 14) + (k << 7) + n];
        _Float16 h = (_Float16)w;
        Wh[idx] = h;
        Wl[idx] = (_Float16)(w - (float)h);
    }
}

// ---------------- fused one-time prep: zero degp, init vn/pooled, xprep, wprep x3, gstart ----------------
__global__ __launch_bounds__(256) void prep_k(
    const float* __restrict__ x, const float* __restrict__ vn_init,
    const float* __restrict__ node_W, const float* __restrict__ mlp1_W, const float* __restrict__ mlp2_W,
    const int* __restrict__ batch,
    int* __restrict__ degp, float* __restrict__ vn, float* __restrict__ pooled8,
    _Float16* __restrict__ X0,
    _Float16* __restrict__ WtN_h, _Float16* __restrict__ WtN_l,
    _Float16* __restrict__ Wt1_h, _Float16* __restrict__ Wt1_l,
    _Float16* __restrict__ Wt2_h, _Float16* __restrict__ Wt2_l,
    int* __restrict__ gstart)
{
    const int gt = blockIdx.x * 256 + threadIdx.x, GT = gridDim.x * 256;
    for (int i = gt; i < 4 * NN16; i += GT) degp[i] = 0;
    for (int i = gt; i < BB * HH; i += GT) vn[i] = vn_init[i & 127];
    for (int i = gt; i < NSHADOW * BB * HH; i += GT) pooled8[i] = 0.f;
    for (int i = gt; i < NN * 32; i += GT) {
        float4 v = ((const float4*)x)[i];
        f16x4 o;
        o[0] = (_Float16)v.x; o[1] = (_Float16)v.y; o[2] = (_Float16)v.z; o[3] = (_Float16)v.w;
        ((f16x4*)X0)[i] = o;
    }
    wprep_dev(node_W, WtN_h, WtN_l, 5 * 16384, gt, GT);
    wprep_dev(mlp1_W, Wt1_h, Wt1_l, 5 * 16384, gt, GT);
    wprep_dev(mlp2_W, Wt2_h, Wt2_l, 5 * 16384, gt, GT);
    if (gt <= BB) {
        if (gt == BB) gstart[BB] = NN;
        else {
            int lo = 0, hi = NN;
            while (lo < hi) {
                int mid = (lo + hi) >> 1;
                if (batch[mid] < gt) lo = mid + 1; else hi = mid;
            }
            gstart[gt] = lo;
        }
    }
}

// ---------------- CSR build ----------------
__global__ void histp_k(const int* __restrict__ idx, int n, int* __restrict__ cntp)
{
    int i = blockIdx.x * 256 + threadIdx.x;
    if (i < n) atomicAdd(&cntp[(blockIdx.x & 3) * NN16 + (idx[i] << 4)], 1);
}

__global__ void scan_deg_k(const int* __restrict__ degp, int n, int* __restrict__ out, int* __restrict__ bsum)
{
    __shared__ int s[256];
    int gid = blockIdx.x * 256 + threadIdx.x;
    int v = 0;
    if (gid < n) {
        int o = gid << 4;
        v = degp[o] + degp[NN16 + o] + degp[2 * NN16 + o] + degp[3 * NN16 + o];
    }
    s[threadIdx.x] = v;
    __syncthreads();
    for (int off = 1; off < 256; off <<= 1) {
        int t = (threadIdx.x >= off) ? s[threadIdx.x - off] : 0;
        __syncthreads();
        s[threadIdx.x] += t;
        __syncthreads();
    }
    int incl = s[threadIdx.x];
    if (gid < n) out[gid] = incl - v;
    if (bsum != nullptr && threadIdx.x == 255) bsum[blockIdx.x] = incl;
}

__global__ void scan_k(const int* __restrict__ in, int n, int* __restrict__ out, int* __restrict__ bsum)
{
    __shared__ int s[256];
    int gid = blockIdx.x * 256 + threadIdx.x;
    int v = (gid < n) ? in[gid] : 0;
    s[threadIdx.x] = v;
    __syncthreads();
    for (int off = 1; off < 256; off <<= 1) {
        int t = (threadIdx.x >= off) ? s[threadIdx.x - off] : 0;
        __syncthreads();
        s[threadIdx.x] += t;
        __syncthreads();
    }
    int incl = s[threadIdx.x];
    if (gid < n) out[gid] = incl - v;
    if (bsum != nullptr && threadIdx.x == 255) bsum[blockIdx.x] = incl;
}

// add block offsets + init padded cursor in one pass
__global__ void addoff_cur_k(int* __restrict__ data, const int* __restrict__ boff, int* __restrict__ cursorp)
{
    int i = blockIdx.x * 256 + threadIdx.x;
    if (i < NN) {
        int v = data[i] + boff[blockIdx.x];
        data[i] = v;
        cursorp[i << 4] = v;
    }
    if (i == 0) data[NN] = EE;
}

__global__ void fill_k(const int* __restrict__ dst, const int* __restrict__ src, int n,
                       int* __restrict__ cursorp, u64* __restrict__ csr)
{
    int e = blockIdx.x * 256 + threadIdx.x;
    if (e < n) {
        int slot = atomicAdd(&cursorp[dst[e] << 4], 1);
        u64 pr = ((u64)(unsigned)e << 32) | (unsigned)src[e];
        __builtin_nontemporal_store(pr, &csr[slot]);
    }
}

// ---------------- aggE[n,16] = sum of eattr over in-edges ----------------
__global__ __launch_bounds__(256) void aggE_k(
    const float* __restrict__ eattr, const int* __restrict__ rowstart,
    const u64* __restrict__ csr, float* __restrict__ aggE)
{
    const int lane = threadIdx.x & 15;
    const int node = blockIdx.x * 16 + (threadIdx.x >> 4);
    if (node >= NN) return;
    const int s = rowstart[node], e = rowstart[node + 1];
    float acc = 0.f;
    for (int p = s; p < e; ++p) {
        u64 v = __builtin_nontemporal_load(&csr[p]);
        acc += eattr[(size_t)(v >> 32) * 16 + lane];
    }
    aggE[(size_t)node * 16 + lane] = acc;
}

// ---------------- node encode: h = fp16(A @ W + b + vn[batch]) ----------------
__global__ __launch_bounds__(256) void gemm_node_k(
    const _Float16* __restrict__ Ag,
    const _Float16* __restrict__ Wh, const _Float16* __restrict__ Wl,
    const float* __restrict__ bias, _Float16* __restrict__ out,
    const float* __restrict__ vn, const int* __restrict__ batch)
{
    __shared__ __align__(16) _Float16 smem[64 * 136];
    const int tid = threadIdx.x, brow = blockIdx.x * 64;
    stage_A16(Ag, brow, tid, smem);
    __syncthreads();
    const int lane = tid & 63, wn = tid >> 6, lm = lane & 15, quad = lane >> 4;
    f32x4 acc[4][2];
#pragma unroll
    for (int mt = 0; mt < 4; ++mt) { acc[mt][0] = (f32x4)(0.f); acc[mt][1] = (f32x4)(0.f); }
    mfma_stage16(smem, Wh, Wl, wn, lm, quad, lane, acc);
    __syncthreads();
    const int colb = wn * 32 + lm;
    const float b0 = bias[colb], b1 = bias[colb + 16];
#pragma unroll
    for (int mt = 0; mt < 4; ++mt) {
#pragma unroll
        for (int r = 0; r < 4; ++r) {
            int trow = mt * 16 + quad * 4 + r;
            int grow = brow + trow;
            int bg = batch[grow < NN ? grow : NN - 1];
            const float* vrow = vn + (size_t)bg * 128;
            smem[trow * 136 + colb]      = (_Float16)(acc[mt][0][r] + b0 + vrow[colb]);
            smem[trow * 136 + colb + 16] = (_Float16)(acc[mt][1][r] + b1 + vrow[colb + 16]);
        }
    }
    __syncthreads();
    store_f16(smem, out, brow, tid);
}

// ---------------- Edge aggregation: fp16 gather-sum + per-node edge term -> fp16 ----------------
__global__ __launch_bounds__(256) void aggregate_k(
    const _Float16* __restrict__ h, const float* __restrict__ aggE,
    const float* __restrict__ eW, const float* __restrict__ eb,
    const int* __restrict__ rowstart, const u64* __restrict__ csr,
    _Float16* __restrict__ Ag)
{
    __shared__ float eWs[16 * 128];
    __shared__ float ebs[128];
    const int tid = threadIdx.x;
#pragma unroll
    for (int t = 0; t < 2; ++t) {
        int li = (tid + t * 256) * 4;
        *(float4*)(&eWs[li]) = *(const float4*)(eW + li);
    }
    if (tid < 32) *(float4*)(&ebs[tid * 4]) = *(const float4*)(eb + tid * 4);
    __syncthreads();
    const int lane = tid & 31;
    const int node = blockIdx.x * 8 + (tid >> 5);
    if (node >= NN) return;
    const int s = rowstart[node], e = rowstart[node + 1];
    const f16x4* h4 = (const f16x4*)h;
    float4 acc = make_float4(0.f, 0.f, 0.f, 0.f);
    int p = s;
    for (; p + 4 <= e; p += 4) {
        u64 c0 = __builtin_nontemporal_load(&csr[p]);
        u64 c1 = __builtin_nontemporal_load(&csr[p + 1]);
        u64 c2 = __builtin_nontemporal_load(&csr[p + 2]);
        u64 c3 = __builtin_nontemporal_load(&csr[p + 3]);
        int s0 = (int)(unsigned)c0, s1 = (int)(unsigned)c1, s2 = (int)(unsigned)c2, s3 = (int)(unsigned)c3;
        f16x4 v0 = h4[(size_t)s0 * 32 + lane];
        f16x4 v1 = h4[(size_t)s1 * 32 + lane];
        f16x4 v2 = h4[(size_t)s2 * 32 + lane];
        f16x4 v3 = h4[(size_t)s3 * 32 + lane];
        acc.x += (float)v0[0] + (float)v1[0] + (float)v2[0] + (float)v3[0];
        acc.y += (float)v0[1] + (float)v1[1] + (float)v2[1] + (float)v3[1];
        acc.z += (float)v0[2] + (float)v1[2] + (float)v2[2] + (float)v3[2];
        acc.w += (float)v0[3] + (float)v1[3] + (float)v2[3] + (float)v3[3];
    }
    for (; p < e; ++p) {
        u64 c = __builtin_nontemporal_load(&csr[p]);
        f16x4 v = h4[(size_t)(unsigned)(c & 0xffffffffu) * 32 + lane];
        acc.x += (float)v[0]; acc.y += (float)v[1]; acc.z += (float)v[2]; acc.w += (float)v[3];
    }
    const float degf = (float)(e - s);
    const float* ae = aggE + (size_t)node * 16;
    const float4 b4 = *(const float4*)(&ebs[lane * 4]);
    float4 et = make_float4(degf * b4.x, degf * b4.y, degf * b4.z, degf * b4.w);
#pragma unroll
    for (int k = 0; k < 16; ++k) {
        float a = ae[k];
        float4 w = *(const float4*)(&eWs[k * 128 + lane * 4]);
        et.x = fmaf(a, w.x, et.x);
        et.y = fmaf(a, w.y, et.y);
        et.z = fmaf(a, w.z, et.z);
        et.w = fmaf(a, w.w, et.w);
    }
    acc.x += et.x; acc.y += et.y; acc.z += et.z; acc.w += et.w;
    f16x4 o;
    o[0] = (_Float16)acc.x; o[1] = (_Float16)acc.y; o[2] = (_Float16)acc.z; o[3] = (_Float16)acc.w;
    ((f16x4*)Ag)[(size_t)node * 32 + lane] = o;
}

// ---------------- fused MLP + pooled partials (shadowed) ----------------
__global__ __launch_bounds__(256) void gemm_mlp_k(
    const _Float16* __restrict__ Ag,
    const _Float16* __restrict__ W1h, const _Float16* __restrict__ W1l, const float* __restrict__ b1,
    const _Float16* __restrict__ W2h, const _Float16* __restrict__ W2l, const float* __restrict__ b2,
    _Float16* __restrict__ X, float* __restrict__ pooled8, const int* __restrict__ batch)
{
    __shared__ __align__(16) _Float16 smem[64 * 136];
    const int tid = threadIdx.x, brow = blockIdx.x * 64;
    stage_A16(Ag, brow, tid, smem);
    __syncthreads();
    const int lane = tid & 63, wn = tid >> 6, lm = lane & 15, quad = lane >> 4;
    const int colb = wn * 32 + lm;
    f32x4 acc[4][2];
#pragma unroll
    for (int mt = 0; mt < 4; ++mt) { acc[mt][0] = (f32x4)(0.f); acc[mt][1] = (f32x4)(0.f); }
    mfma_stage16(smem, W1h, W1l, wn, lm, quad, lane, acc);
    __syncthreads();
    {
        const float c0 = b1[colb], c1 = b1[colb + 16];
#pragma unroll
        for (int mt = 0; mt < 4; ++mt) {
#pragma unroll
            for (int r = 0; r < 4; ++r) {
                int trow = mt * 16 + quad * 4 + r;
                smem[trow * 136 + colb]      = (_Float16)fmaxf(acc[mt][0][r] + c0, 0.f);
                smem[trow * 136 + colb + 16] = (_Float16)fmaxf(acc[mt][1][r] + c1, 0.f);
            }
        }
    }
    __syncthreads();
#pragma unroll
    for (int mt = 0; mt < 4; ++mt) { acc[mt][0] = (f32x4)(0.f); acc[mt][1] = (f32x4)(0.f); }
    mfma_stage16(smem, W2h, W2l, wn, lm, quad, lane, acc);
    __syncthreads();
    {
        const float d0 = b2[colb], d1 = b2[colb + 16];
#pragma unroll
        for (int mt = 0; mt < 4; ++mt) {
#pragma unroll
            for (int r = 0; r < 4; ++r) {
                int trow = mt * 16 + quad * 4 + r;
                smem[trow * 136 + colb]      = (_Float16)fmaxf(acc[mt][0][r] + d0, 0.f);
                smem[trow * 136 + colb + 16] = (_Float16)fmaxf(acc[mt][1][r] + d1, 0.f);
            }
        }
    }
    __syncthreads();
    store_f16(smem, X, brow, tid);
    {
        float* pooled = pooled8 + (size_t)(blockIdx.x & (NSHADOW - 1)) * (BB * HH);
        const int c = tid & 127, half = tid >> 7;
        const int row0 = half * 32;
        float sum = 0.f;
        int curg = -1;
        for (int r2 = 0; r2 < 32; ++r2) {
            int grow = brow + row0 + r2;
            if (grow >= NN) break;
            int g = batch[grow];
            if (g != curg) {
                if (curg >= 0) atomicAdd(&pooled[curg * 128 + c], sum);
                curg = g; sum = 0.f;
            }
            sum += (float)smem[(row0 + r2) * 136 + c];
        }
        if (curg >= 0) atomicAdd(&pooled[curg * 128 + c], sum);
    }
}

// ---------------- VN update (clears pooled shadows) ----------------
__global__ __launch_bounds__(128) void vn_update_k(
    float* __restrict__ pooled8, const int* __restrict__ gstart,
    const float* __restrict__ W0, const float* __restrict__ b0,
    const float* __restrict__ W1, const float* __restrict__ b1,
    float* __restrict__ vn)
{
    __shared__ float p[128], q[128];
    const int g = blockIdx.x, t = threadIdx.x;
    float cnt = (float)(gstart[g + 1] - gstart[g]);
    if (cnt < 1.f) cnt = 1.f;
    float sum = 0.f;
#pragma unroll
    for (int s = 0; s < NSHADOW; ++s) {
        float* slot = pooled8 + (size_t)s * (BB * HH) + g * 128 + t;
        sum += *slot;
        *slot = 0.f;
    }
    p[t] = sum / cnt;
    __syncthreads();
    float a0 = b0[t];
    for (int k = 0; k < 128; ++k) a0 = fmaf(p[k], W0[k * 128 + t], a0);
    q[t] = fmaxf(a0, 0.f);
    __syncthreads();
    float a1 = b1[t];
    for (int k = 0; k < 128; ++k) a1 = fmaf(q[k], W1[k * 128 + t], a1);
    vn[g * 128 + t] += fmaxf(a1, 0.f);
}

// ---------------- final classifier ----------------
__global__ __launch_bounds__(128) void fc_k(
    const float* __restrict__ pooled8, const int* __restrict__ gstart,
    const float* __restrict__ W, const float* __restrict__ b, float* __restrict__ out)
{
    __shared__ float p[128];
    const int g = blockIdx.x, t = threadIdx.x;
    float cnt = (float)(gstart[g + 1] - gstart[g]);
    if (cnt < 1.f) cnt = 1.f;
    float sum = 0.f;
#pragma unroll
    for (int s = 0; s < NSHADOW; ++s)
        sum += pooled8[(size_t)s * (BB * HH) + g * 128 + t];
    p[t] = sum / cnt;
    __syncthreads();
    float acc = b[t];
    for (int k = 0; k < 128; ++k) acc = fmaf(p[k], W[k * 128 + t], acc);
    out[g * 128 + t] = acc;
}

// ---------------- Launch ----------------
extern "C" void kernel_launch(void* const* d_in, const int* in_sizes, int n_in,
                              void* d_out, int out_size, void* d_ws, size_t ws_size,
                              hipStream_t stream)
{
    (void)in_sizes; (void)n_in; (void)out_size; (void)ws_size;
    const float* x       = (const float*)d_in[0];
    const float* eattr   = (const float*)d_in[1];
    const float* node_W  = (const float*)d_in[2];
    const float* node_b  = (const float*)d_in[3];
    const float* edge_W  = (const float*)d_in[4];
    const float* edge_b  = (const float*)d_in[5];
    const float* mlp1_W  = (const float*)d_in[6];
    const float* mlp1_b  = (const float*)d_in[7];
    const float* mlp2_W  = (const float*)d_in[8];
    const float* mlp2_b  = (const float*)d_in[9];
    const float* vn_w0   = (const float*)d_in[10];
    const float* vn_b0   = (const float*)d_in[11];
    const float* vn_w1   = (const float*)d_in[12];
    const float* vn_b1   = (const float*)d_in[13];
    const float* fc_W    = (const float*)d_in[14];
    const float* fc_b    = (const float*)d_in[15];
    const float* vn_init = (const float*)d_in[16];
    const int*   eidx    = (const int*)d_in[17];
    const int*   batch   = (const int*)d_in[18];
    const int* srcv = eidx;
    const int* dstv = eidx + EE;

    char* wp = (char*)d_ws;
    auto alloc = [&](size_t bytes) -> void* {
        void* p = (void*)wp;
        wp += (bytes + 255) & ~(size_t)255;
        return p;
    };
    _Float16* X0  = (_Float16*)alloc((size_t)NN * HH * 2);
    _Float16* X   = (_Float16*)alloc((size_t)NN * HH * 2);
    _Float16* Ag  = (_Float16*)alloc((size_t)NN * HH * 2);
    _Float16* h16 = (_Float16*)alloc((size_t)NN * HH * 2);
    float* aggE   = (float*)alloc((size_t)NN * EDD * 4);
    float* vn     = (float*)alloc((size_t)BB * HH * 4);
    float* pooled8= (float*)alloc((size_t)NSHADOW * BB * HH * 4);
    int* degp     = (int*)alloc((size_t)4 * NN16 * 4);
    int* rowstart = (int*)alloc((size_t)(NN + 1) * 4);
    int* cursorp  = (int*)alloc((size_t)NN16 * 4);
    u64* csr      = (u64*)alloc((size_t)EE * 8);
    int* bsum     = (int*)alloc(256 * 4);
    int* boff     = (int*)alloc(256 * 4);
    int* gstart   = (int*)alloc((size_t)(BB + 1) * 4);
    _Float16* WtN_h = (_Float16*)alloc((size_t)5 * 16384 * 2);
    _Float16* WtN_l = (_Float16*)alloc((size_t)5 * 16384 * 2);
    _Float16* Wt1_h = (_Float16*)alloc((size_t)5 * 16384 * 2);
    _Float16* Wt1_l = (_Float16*)alloc((size_t)5 * 16384 * 2);
    _Float16* Wt2_h = (_Float16*)alloc((size_t)5 * 16384 * 2);
    _Float16* Wt2_l = (_Float16*)alloc((size_t)5 * 16384 * 2);

    // setup: 7 dispatches
    prep_k<<<2048, 256, 0, stream>>>(x, vn_init, node_W, mlp1_W, mlp2_W, batch,
                                     degp, vn, pooled8, X0,
                                     WtN_h, WtN_l, Wt1_h, Wt1_l, Wt2_h, Wt2_l, gstart);
    histp_k<<<(EE + 255) / 256, 256, 0, stream>>>(dstv, EE, degp);
    const int NB1 = (NN + 255) / 256;
    scan_deg_k<<<NB1, 256, 0, stream>>>(degp, NN, rowstart, bsum);
    scan_k<<<1, 256, 0, stream>>>(bsum, NB1, boff, nullptr);
    addoff_cur_k<<<NB1, 256, 0, stream>>>(rowstart, boff, cursorp);
    fill_k<<<(EE + 255) / 256, 256, 0, stream>>>(dstv, srcv, EE, cursorp, csr);
    aggE_k<<<(NN + 15) / 16, 256, 0, stream>>>(eattr, rowstart, csr, aggE);

    const int GN = (NN + 63) / 64;
    const _Float16* xin = X0;
    for (int l = 0; l < LL; ++l) {
        gemm_node_k<<<GN, 256, 0, stream>>>(xin,
            WtN_h + (size_t)l * 16384, WtN_l + (size_t)l * 16384,
            node_b + (size_t)l * HH, h16, vn, batch);
        aggregate_k<<<(NN + 7) / 8, 256, 0, stream>>>(h16, aggE,
            edge_W + (size_t)l * EDD * HH, edge_b + (size_t)l * HH,
            rowstart, csr, Ag);
        gemm_mlp_k<<<GN, 256, 0, stream>>>(Ag,
            Wt1_h + (size_t)l * 16384, Wt1_l + (size_t)l * 16384, mlp1_b + (size_t)l * HH,
            Wt2_h + (size_t)l * 16384, Wt2_l + (size_t)l * 16384, mlp2_b + (size_t)l * HH,
            X, pooled8, batch);
        if (l < LL - 1)
            vn_update_k<<<BB, 128, 0, stream>>>(pooled8, gstart, vn_w0, vn_b0, vn_w1, vn_b1, vn);
        xin = X;
    }
    fc_k<<<BB, 128, 0, stream>>>(pooled8, gstart, fc_W, fc_b, (float*)d_out);
}